// Round 1
// baseline (958.511 us; speedup 1.0000x reference)
//
#include <hip/hip_runtime.h>
#include <hip/hip_bf16.h>

typedef __attribute__((ext_vector_type(8))) short s8v;   // 8 bf16 in 4 VGPRs
typedef __attribute__((ext_vector_type(4))) float f4v;   // 4 fp32 acc

__device__ __forceinline__ void gl_lds16(const void* g, void* l) {
  __builtin_amdgcn_global_load_lds(
      (const __attribute__((address_space(1))) unsigned int*)g,
      (__attribute__((address_space(3))) unsigned int*)l, 16, 0, 0);
}

__device__ __forceinline__ unsigned short f2b(float v) {
  __hip_bfloat16 b = __float2bfloat16(v);  // RNE
  return __builtin_bit_cast(unsigned short, b);
}

__device__ __forceinline__ float sigm(float x) { return 1.0f / (1.0f + __expf(-x)); }
__device__ __forceinline__ float tanh_f(float x) {
  float e = __expf(-2.0f * fabsf(x));
  float t = (1.0f - e) / (1.0f + e);
  return x >= 0.0f ? t : -t;
}

// ---------------- prep kernels ----------------

__global__ void k_conv_bf16(const float* __restrict__ src, unsigned short* __restrict__ dst, int n) {
  int i = blockIdx.x * blockDim.x + threadIdx.x;
  if (i < n) dst[i] = f2b(src[i]);
}

// W1x[n][k] = bf16(W1[n][17+k]) for k in [0,256); b1e[n] = b1[n] + W1[n][20 - slen]
__global__ void k_prep_w1(const float* __restrict__ W1, const float* __restrict__ b1,
                          const int* __restrict__ slen,
                          unsigned short* __restrict__ W1x, float* __restrict__ b1e) {
  int i = blockIdx.x * blockDim.x + threadIdx.x;
  if (i < 512 * 256) {
    int n = i >> 8, k = i & 255;
    W1x[i] = f2b(W1[n * 273 + 17 + k]);
  }
  if (i < 512) {
    int col = 20 - *slen;
    b1e[i] = b1[i] + W1[i * 273 + col];
  }
}

// Wihb = bf16(Wih); Wsum = bf16(Wih+Whh); biasg = bih+bhh
__global__ void k_prep_gates(const float* __restrict__ Wih, const float* __restrict__ Whh,
                             const float* __restrict__ bih, const float* __restrict__ bhh,
                             unsigned short* __restrict__ Wihb, unsigned short* __restrict__ Wsum,
                             float* __restrict__ biasg) {
  int i = blockIdx.x * blockDim.x + threadIdx.x;
  if (i < 2048 * 512) {
    float a = Wih[i];
    Wihb[i] = f2b(a);
    Wsum[i] = f2b(a + Whh[i]);
  }
  if (i < 2048) biasg[i] = bih[i] + bhh[i];
}

// ---------------- GEMM C = act(A @ Bt^T + bias), A:[M,K] bf16, Bt:[N,K] bf16 ----------------
// 128x128 tile, BK=32, 256 threads (4 waves in 2x2), 16x16x32 bf16 MFMA.
// ACT: 0 = relu, 1 = sigmoid. Output bf16.

template <int ACT>
__global__ __launch_bounds__(256)
void k_gemm_bt(const unsigned short* __restrict__ A, const unsigned short* __restrict__ Bt,
               const float* __restrict__ bias, unsigned short* __restrict__ C,
               int M, int N, int K) {
  __shared__ __align__(16) unsigned short As[128 * 32];
  __shared__ __align__(16) unsigned short Bs[128 * 32];
  const int tid = threadIdx.x;
  const int m0 = blockIdx.y * 128, n0 = blockIdx.x * 128;
  const int lane = tid & 63, wave = tid >> 6;
  const int wm = (wave >> 1) * 64, wn = (wave & 1) * 64;
  const int lr = lane & 15, lq = lane >> 4;

  f4v acc[4][4];
#pragma unroll
  for (int i = 0; i < 4; ++i)
#pragma unroll
    for (int j = 0; j < 4; ++j) acc[i][j] = (f4v){0.f, 0.f, 0.f, 0.f};

  for (int k0 = 0; k0 < K; k0 += 32) {
    __syncthreads();  // previous iter's LDS consumers done
#pragma unroll
    for (int s = 0; s < 2; ++s) {
      int cc = tid + s * 256;          // chunk index; lane-contiguous within wave
      int row = cc >> 2, kk = (cc & 3) << 3;
      gl_lds16(&A[(long)(m0 + row) * K + k0 + kk], &As[cc * 8]);
      gl_lds16(&Bt[(long)(n0 + row) * K + k0 + kk], &Bs[cc * 8]);
    }
    __syncthreads();  // drains vmcnt -> LDS valid

    s8v a[4], b[4];
#pragma unroll
    for (int i = 0; i < 4; ++i)
      a[i] = *(const s8v*)&As[(wm + i * 16 + lr) * 32 + lq * 8];
#pragma unroll
    for (int j = 0; j < 4; ++j)
      b[j] = *(const s8v*)&Bs[(wn + j * 16 + lr) * 32 + lq * 8];
#pragma unroll
    for (int i = 0; i < 4; ++i)
#pragma unroll
      for (int j = 0; j < 4; ++j)
        acc[i][j] = __builtin_amdgcn_mfma_f32_16x16x32_bf16(a[i], b[j], acc[i][j], 0, 0, 0);
  }

#pragma unroll
  for (int i = 0; i < 4; ++i) {
#pragma unroll
    for (int j = 0; j < 4; ++j) {
#pragma unroll
      for (int r = 0; r < 4; ++r) {
        int m = m0 + wm + i * 16 + lq * 4 + r;
        int n = n0 + wn + j * 16 + lr;
        float v = acc[i][j][r] + bias[n];
        v = (ACT == 0) ? fmaxf(v, 0.0f) : sigm(v);
        C[(long)m * N + n] = f2b(v);
      }
    }
  }
}

// ---------------- fused LSTM step ----------------
// gates[:, g*512+u] = A @ Wg^T + bias; cell epilogue entirely in-register.
// Block: 128 rows x 32 units x 4 gates. Grid (512/32, M/128). 4 waves split rows.

__global__ __launch_bounds__(256)
void k_lstm_step(const unsigned short* __restrict__ A,   // [M,512] bf16 (h_prev or x0)
                 const unsigned short* __restrict__ Wg,  // [2048,512] bf16
                 const float* __restrict__ bias,         // [2048] = bih+bhh
                 float* __restrict__ Cst,                // [M,512] fp32 cell state
                 unsigned short* __restrict__ Hout,      // [M,512] bf16 next input
                 float* __restrict__ Out,                // [M,T,512] fp32
                 int T, int t, int first) {
  __shared__ __align__(16) unsigned short As[128 * 32];
  __shared__ __align__(16) unsigned short Bs[4 * 32 * 32];
  const int tid = threadIdx.x;
  const int m0 = blockIdx.y * 128;
  const int n0 = blockIdx.x * 32;
  const int lane = tid & 63, wave = tid >> 6;
  const int lr = lane & 15, lq = lane >> 4;
  const int wrow = wave * 32;
  const int K = 512;

  f4v acc[4][2][2];  // [gate][row-tile][col-tile]
#pragma unroll
  for (int g = 0; g < 4; ++g)
#pragma unroll
    for (int i = 0; i < 2; ++i)
#pragma unroll
      for (int j = 0; j < 2; ++j) acc[g][i][j] = (f4v){0.f, 0.f, 0.f, 0.f};

  for (int k0 = 0; k0 < K; k0 += 32) {
    __syncthreads();
#pragma unroll
    for (int s = 0; s < 2; ++s) {
      int cc = tid + s * 256;
      {  // A tile: 128x32
        int row = cc >> 2, kk = (cc & 3) << 3;
        gl_lds16(&A[(long)(m0 + row) * K + k0 + kk], &As[cc * 8]);
      }
      {  // B tiles: 4 gates x 32x32, gathered from rows g*512+n0..
        int g = cc >> 7, idx = cc & 127;
        int row = idx >> 2, kk = (idx & 3) << 3;
        gl_lds16(&Wg[(long)(g * 512 + n0 + row) * K + k0 + kk], &Bs[cc * 8]);
      }
    }
    __syncthreads();

    s8v a[2], b[4][2];
#pragma unroll
    for (int i = 0; i < 2; ++i)
      a[i] = *(const s8v*)&As[(wrow + i * 16 + lr) * 32 + lq * 8];
#pragma unroll
    for (int g = 0; g < 4; ++g)
#pragma unroll
      for (int j = 0; j < 2; ++j)
        b[g][j] = *(const s8v*)&Bs[g * 1024 + (j * 16 + lr) * 32 + lq * 8];
#pragma unroll
    for (int g = 0; g < 4; ++g)
#pragma unroll
      for (int i = 0; i < 2; ++i)
#pragma unroll
        for (int j = 0; j < 2; ++j)
          acc[g][i][j] = __builtin_amdgcn_mfma_f32_16x16x32_bf16(a[i], b[g][j], acc[g][i][j], 0, 0, 0);
  }

#pragma unroll
  for (int i = 0; i < 2; ++i) {
#pragma unroll
    for (int j = 0; j < 2; ++j) {
#pragma unroll
      for (int r = 0; r < 4; ++r) {
        int m = m0 + wrow + i * 16 + lq * 4 + r;
        int u = n0 + j * 16 + lr;
        float gi = acc[0][i][j][r] + bias[u];
        float gf = acc[1][i][j][r] + bias[512 + u];
        float gg = acc[2][i][j][r] + bias[1024 + u];
        float go = acc[3][i][j][r] + bias[1536 + u];
        float c_old = first ? 0.0f : Cst[(long)m * 512 + u];
        float cn = sigm(gf) * c_old + sigm(gi) * tanh_f(gg);
        float h = sigm(go) * tanh_f(cn);
        Cst[(long)m * 512 + u] = cn;
        Hout[(long)m * 512 + u] = f2b(h);
        Out[((long)m * T + t) * 512 + u] = h;
      }
    }
  }
}

// ---------------- launch ----------------

extern "C" void kernel_launch(void* const* d_in, const int* in_sizes, int n_in,
                              void* d_out, int out_size, void* d_ws, size_t ws_size,
                              hipStream_t stream) {
  const float* x   = (const float*)d_in[0];
  const float* W1  = (const float*)d_in[1];
  const float* b1  = (const float*)d_in[2];
  const float* W2  = (const float*)d_in[3];
  const float* b2  = (const float*)d_in[4];
  const float* W3  = (const float*)d_in[5];
  const float* b3  = (const float*)d_in[6];
  const float* Wih = (const float*)d_in[7];
  const float* Whh = (const float*)d_in[8];
  const float* bih = (const float*)d_in[9];
  const float* bhh = (const float*)d_in[10];
  const int* slen  = (const int*)d_in[11];
  float* out = (float*)d_out;

  const int B = in_sizes[0] / 256;     // 8192
  const int T = out_size / (B * 512);  // = sentence_len = 16

  // workspace carve (256B aligned)
  size_t o = 0;
  auto alloc = [&](size_t bytes) {
    o = (o + 255) & ~(size_t)255;
    void* r = (char*)d_ws + o;
    o += bytes;
    return r;
  };
  unsigned short* xb    = (unsigned short*)alloc((size_t)B * 256 * 2);
  unsigned short* W1x   = (unsigned short*)alloc(512 * 256 * 2);
  unsigned short* W2b   = (unsigned short*)alloc(512 * 512 * 2);
  unsigned short* W3b   = (unsigned short*)alloc(512 * 512 * 2);
  unsigned short* Wihb  = (unsigned short*)alloc(2048 * 512 * 2);
  unsigned short* Wsumb = (unsigned short*)alloc(2048 * 512 * 2);
  float* b1e   = (float*)alloc(512 * 4);
  float* biasg = (float*)alloc(2048 * 4);
  unsigned short* h1 = (unsigned short*)alloc((size_t)B * 512 * 2);
  unsigned short* h2 = (unsigned short*)alloc((size_t)B * 512 * 2);
  float* cbuf = (float*)alloc((size_t)B * 512 * 4);
  (void)ws_size;

  // prep
  k_conv_bf16<<<(B * 256 + 255) / 256, 256, 0, stream>>>(x, xb, B * 256);
  k_conv_bf16<<<(512 * 512 + 255) / 256, 256, 0, stream>>>(W2, W2b, 512 * 512);
  k_conv_bf16<<<(512 * 512 + 255) / 256, 256, 0, stream>>>(W3, W3b, 512 * 512);
  k_prep_w1<<<(512 * 256 + 255) / 256, 256, 0, stream>>>(W1, b1, slen, W1x, b1e);
  k_prep_gates<<<(2048 * 512 + 255) / 256, 256, 0, stream>>>(Wih, Whh, bih, bhh, Wihb, Wsumb, biasg);

  // MLP: h1 = relu(x@W1x^T + b1e); h2 = relu(h1@W2^T + b2); x0 = sigmoid(h2@W3^T + b3) -> h1
  k_gemm_bt<0><<<dim3(4, B / 128), 256, 0, stream>>>(xb, W1x, b1e, h1, B, 512, 256);
  k_gemm_bt<0><<<dim3(4, B / 128), 256, 0, stream>>>(h1, W2b, b2, h2, B, 512, 512);
  k_gemm_bt<1><<<dim3(4, B / 128), 256, 0, stream>>>(h2, W3b, b3, h1, B, 512, 512);

  // LSTM: step 0 uses Wih only (h0=0, c0=0); steps >=1 use Wih+Whh since inp==h.
  for (int t = 0; t < T; ++t) {
    const unsigned short* a = (t % 2 == 0) ? h1 : h2;
    unsigned short* ho      = (t % 2 == 0) ? h2 : h1;
    k_lstm_step<<<dim3(512 / 32, B / 128), 256, 0, stream>>>(
        a, (t == 0) ? Wihb : Wsumb, biasg, cbuf, ho, out, T, t, (t == 0) ? 1 : 0);
  }
}

// Round 3
// 933.161 us; speedup vs baseline: 1.0272x; 1.0272x over previous
//
#include <hip/hip_runtime.h>
#include <hip/hip_bf16.h>

typedef __attribute__((ext_vector_type(8))) short s8v;   // 8 bf16 in 4 VGPRs
typedef __attribute__((ext_vector_type(4))) float f4v;   // 4 fp32 acc

__device__ __forceinline__ void gl_lds16(const void* g, void* l) {
  __builtin_amdgcn_global_load_lds(
      (const __attribute__((address_space(1))) unsigned int*)g,
      (__attribute__((address_space(3))) unsigned int*)l, 16, 0, 0);
}

__device__ __forceinline__ unsigned short f2b(float v) {
  __hip_bfloat16 b = __float2bfloat16(v);  // RNE
  return __builtin_bit_cast(unsigned short, b);
}

// sigm(x) = 1/(1+2^(-x*log2e)) : 2 transcendental + 2 VALU (no div sequence)
__device__ __forceinline__ float sigm(float x) {
  float e = __builtin_amdgcn_exp2f(-1.442695041f * x);
  return __builtin_amdgcn_rcpf(1.0f + e);
}
// tanh(x) = 2*sigm(2x) - 1, saturates cleanly at +-1
__device__ __forceinline__ float tanh_f(float x) {
  float e = __builtin_amdgcn_exp2f(-2.885390082f * x);
  return __builtin_fmaf(2.0f, __builtin_amdgcn_rcpf(1.0f + e), -1.0f);
}

// ---------------- prep kernels ----------------

__global__ void k_conv_bf16(const float* __restrict__ src, unsigned short* __restrict__ dst, int n) {
  int i = blockIdx.x * blockDim.x + threadIdx.x;
  if (i < n) dst[i] = f2b(src[i]);
}

// W1x[n][k] = bf16(W1[n][17+k]) for k in [0,256); b1e[n] = b1[n] + W1[n][20 - slen]
__global__ void k_prep_w1(const float* __restrict__ W1, const float* __restrict__ b1,
                          const int* __restrict__ slen,
                          unsigned short* __restrict__ W1x, float* __restrict__ b1e) {
  int i = blockIdx.x * blockDim.x + threadIdx.x;
  if (i < 512 * 256) {
    int n = i >> 8, k = i & 255;
    W1x[i] = f2b(W1[n * 273 + 17 + k]);
  }
  if (i < 512) {
    int col = 20 - *slen;
    b1e[i] = b1[i] + W1[i * 273 + col];
  }
}

// Wihb = bf16(Wih); Wsum = bf16(Wih+Whh); biasg = bih+bhh
__global__ void k_prep_gates(const float* __restrict__ Wih, const float* __restrict__ Whh,
                             const float* __restrict__ bih, const float* __restrict__ bhh,
                             unsigned short* __restrict__ Wihb, unsigned short* __restrict__ Wsum,
                             float* __restrict__ biasg) {
  int i = blockIdx.x * blockDim.x + threadIdx.x;
  if (i < 2048 * 512) {
    float a = Wih[i];
    Wihb[i] = f2b(a);
    Wsum[i] = f2b(a + Whh[i]);
  }
  if (i < 2048) biasg[i] = bih[i] + bhh[i];
}

// ---------------- GEMM C = act(A @ Bt^T + bias), A:[M,K] bf16, Bt:[N,K] bf16 ----------------
// 128x128 tile, BK=32, 256 threads (4 waves in 2x2), 16x16x32 bf16 MFMA.
// ACT: 0 = relu, 1 = sigmoid. Output bf16.

template <int ACT>
__global__ __launch_bounds__(256)
void k_gemm_bt(const unsigned short* __restrict__ A, const unsigned short* __restrict__ Bt,
               const float* __restrict__ bias, unsigned short* __restrict__ C,
               int M, int N, int K) {
  __shared__ __align__(16) unsigned short As[128 * 32];
  __shared__ __align__(16) unsigned short Bs[128 * 32];
  const int tid = threadIdx.x;
  const int m0 = blockIdx.y * 128, n0 = blockIdx.x * 128;
  const int lane = tid & 63, wave = tid >> 6;
  const int wm = (wave >> 1) * 64, wn = (wave & 1) * 64;
  const int lr = lane & 15, lq = lane >> 4;

  f4v acc[4][4];
#pragma unroll
  for (int i = 0; i < 4; ++i)
#pragma unroll
    for (int j = 0; j < 4; ++j) acc[i][j] = (f4v){0.f, 0.f, 0.f, 0.f};

  for (int k0 = 0; k0 < K; k0 += 32) {
    __syncthreads();  // previous iter's LDS consumers done
#pragma unroll
    for (int s = 0; s < 2; ++s) {
      int cc = tid + s * 256;          // chunk index; lane-contiguous within wave
      int row = cc >> 2, kk = (cc & 3) << 3;
      gl_lds16(&A[(long)(m0 + row) * K + k0 + kk], &As[cc * 8]);
      gl_lds16(&Bt[(long)(n0 + row) * K + k0 + kk], &Bs[cc * 8]);
    }
    __syncthreads();  // drains vmcnt -> LDS valid

    s8v a[4], b[4];
#pragma unroll
    for (int i = 0; i < 4; ++i)
      a[i] = *(const s8v*)&As[(wm + i * 16 + lr) * 32 + lq * 8];
#pragma unroll
    for (int j = 0; j < 4; ++j)
      b[j] = *(const s8v*)&Bs[(wn + j * 16 + lr) * 32 + lq * 8];
#pragma unroll
    for (int i = 0; i < 4; ++i)
#pragma unroll
      for (int j = 0; j < 4; ++j)
        acc[i][j] = __builtin_amdgcn_mfma_f32_16x16x32_bf16(a[i], b[j], acc[i][j], 0, 0, 0);
  }

#pragma unroll
  for (int i = 0; i < 4; ++i) {
#pragma unroll
    for (int j = 0; j < 4; ++j) {
#pragma unroll
      for (int r = 0; r < 4; ++r) {
        int m = m0 + wm + i * 16 + lq * 4 + r;
        int n = n0 + wn + j * 16 + lr;
        float v = acc[i][j][r] + bias[n];
        v = (ACT == 0) ? fmaxf(v, 0.0f) : sigm(v);
        C[(long)m * N + n] = f2b(v);
      }
    }
  }
}

// ---------------- fused LSTM step ----------------
// gates[:, g*512+u] = A @ Wg^T + bias; cell epilogue entirely in-register.
// Block: 128 rows x 32 units x 4 gates. Grid (512/32, M/128). 4 waves split rows.

__global__ __launch_bounds__(256)
void k_lstm_step(const unsigned short* __restrict__ A,   // [M,512] bf16 (h_prev or x0)
                 const unsigned short* __restrict__ Wg,  // [2048,512] bf16
                 const float* __restrict__ bias,         // [2048] = bih+bhh
                 float* __restrict__ Cst,                // [M,512] fp32 cell state
                 unsigned short* __restrict__ Hout,      // [M,512] bf16 next input
                 float* __restrict__ Out,                // [M,T,512] fp32
                 int T, int t, int first) {
  __shared__ __align__(16) unsigned short As[128 * 32];
  __shared__ __align__(16) unsigned short Bs[4 * 32 * 32];
  const int tid = threadIdx.x;
  const int m0 = blockIdx.y * 128;
  const int n0 = blockIdx.x * 32;
  const int lane = tid & 63, wave = tid >> 6;
  const int lr = lane & 15, lq = lane >> 4;
  const int wrow = wave * 32;
  const int K = 512;

  f4v acc[4][2][2];  // [gate][row-tile][col-tile]
#pragma unroll
  for (int g = 0; g < 4; ++g)
#pragma unroll
    for (int i = 0; i < 2; ++i)
#pragma unroll
      for (int j = 0; j < 2; ++j) acc[g][i][j] = (f4v){0.f, 0.f, 0.f, 0.f};

  for (int k0 = 0; k0 < K; k0 += 32) {
    __syncthreads();
#pragma unroll
    for (int s = 0; s < 2; ++s) {
      int cc = tid + s * 256;
      {  // A tile: 128x32
        int row = cc >> 2, kk = (cc & 3) << 3;
        gl_lds16(&A[(long)(m0 + row) * K + k0 + kk], &As[cc * 8]);
      }
      {  // B tiles: 4 gates x 32x32, gathered from rows g*512+n0..
        int g = cc >> 7, idx = cc & 127;
        int row = idx >> 2, kk = (idx & 3) << 3;
        gl_lds16(&Wg[(long)(g * 512 + n0 + row) * K + k0 + kk], &Bs[cc * 8]);
      }
    }
    __syncthreads();

    s8v a[2], b[4][2];
#pragma unroll
    for (int i = 0; i < 2; ++i)
      a[i] = *(const s8v*)&As[(wrow + i * 16 + lr) * 32 + lq * 8];
#pragma unroll
    for (int g = 0; g < 4; ++g)
#pragma unroll
      for (int j = 0; j < 2; ++j)
        b[g][j] = *(const s8v*)&Bs[g * 1024 + (j * 16 + lr) * 32 + lq * 8];
#pragma unroll
    for (int g = 0; g < 4; ++g)
#pragma unroll
      for (int i = 0; i < 2; ++i)
#pragma unroll
        for (int j = 0; j < 2; ++j)
          acc[g][i][j] = __builtin_amdgcn_mfma_f32_16x16x32_bf16(a[i], b[g][j], acc[g][i][j], 0, 0, 0);
  }

#pragma unroll
  for (int i = 0; i < 2; ++i) {
#pragma unroll
    for (int j = 0; j < 2; ++j) {
#pragma unroll
      for (int r = 0; r < 4; ++r) {
        int m = m0 + wrow + i * 16 + lq * 4 + r;
        int u = n0 + j * 16 + lr;
        float gi = acc[0][i][j][r] + bias[u];
        float gf = acc[1][i][j][r] + bias[512 + u];
        float gg = acc[2][i][j][r] + bias[1024 + u];
        float go = acc[3][i][j][r] + bias[1536 + u];
        float c_old = first ? 0.0f : Cst[(long)m * 512 + u];
        float cn = sigm(gf) * c_old + sigm(gi) * tanh_f(gg);
        float h = sigm(go) * tanh_f(cn);
        Cst[(long)m * 512 + u] = cn;
        Hout[(long)m * 512 + u] = f2b(h);
        Out[((long)m * T + t) * 512 + u] = h;
      }
    }
  }
}

// ---------------- launch ----------------

extern "C" void kernel_launch(void* const* d_in, const int* in_sizes, int n_in,
                              void* d_out, int out_size, void* d_ws, size_t ws_size,
                              hipStream_t stream) {
  const float* x   = (const float*)d_in[0];
  const float* W1  = (const float*)d_in[1];
  const float* b1  = (const float*)d_in[2];
  const float* W2  = (const float*)d_in[3];
  const float* b2  = (const float*)d_in[4];
  const float* W3  = (const float*)d_in[5];
  const float* b3  = (const float*)d_in[6];
  const float* Wih = (const float*)d_in[7];
  const float* Whh = (const float*)d_in[8];
  const float* bih = (const float*)d_in[9];
  const float* bhh = (const float*)d_in[10];
  const int* slen  = (const int*)d_in[11];
  float* out = (float*)d_out;

  const int B = in_sizes[0] / 256;     // 8192
  const int T = out_size / (B * 512);  // = sentence_len = 16

  // workspace carve (256B aligned)
  size_t o = 0;
  auto alloc = [&](size_t bytes) {
    o = (o + 255) & ~(size_t)255;
    void* r = (char*)d_ws + o;
    o += bytes;
    return r;
  };
  unsigned short* xb    = (unsigned short*)alloc((size_t)B * 256 * 2);
  unsigned short* W1x   = (unsigned short*)alloc(512 * 256 * 2);
  unsigned short* W2b   = (unsigned short*)alloc(512 * 512 * 2);
  unsigned short* W3b   = (unsigned short*)alloc(512 * 512 * 2);
  unsigned short* Wihb  = (unsigned short*)alloc(2048 * 512 * 2);
  unsigned short* Wsumb = (unsigned short*)alloc(2048 * 512 * 2);
  float* b1e   = (float*)alloc(512 * 4);
  float* biasg = (float*)alloc(2048 * 4);
  unsigned short* h1 = (unsigned short*)alloc((size_t)B * 512 * 2);
  unsigned short* h2 = (unsigned short*)alloc((size_t)B * 512 * 2);
  float* cbuf = (float*)alloc((size_t)B * 512 * 4);
  (void)ws_size;

  // prep
  k_conv_bf16<<<(B * 256 + 255) / 256, 256, 0, stream>>>(x, xb, B * 256);
  k_conv_bf16<<<(512 * 512 + 255) / 256, 256, 0, stream>>>(W2, W2b, 512 * 512);
  k_conv_bf16<<<(512 * 512 + 255) / 256, 256, 0, stream>>>(W3, W3b, 512 * 512);
  k_prep_w1<<<(512 * 256 + 255) / 256, 256, 0, stream>>>(W1, b1, slen, W1x, b1e);
  k_prep_gates<<<(2048 * 512 + 255) / 256, 256, 0, stream>>>(Wih, Whh, bih, bhh, Wihb, Wsumb, biasg);

  // MLP: h1 = relu(x@W1x^T + b1e); h2 = relu(h1@W2^T + b2); x0 = sigmoid(h2@W3^T + b3) -> h1
  k_gemm_bt<0><<<dim3(4, B / 128), 256, 0, stream>>>(xb, W1x, b1e, h1, B, 512, 256);
  k_gemm_bt<0><<<dim3(4, B / 128), 256, 0, stream>>>(h1, W2b, b2, h2, B, 512, 512);
  k_gemm_bt<1><<<dim3(4, B / 128), 256, 0, stream>>>(h2, W3b, b3, h1, B, 512, 512);

  // LSTM: step 0 uses Wih only (h0=0, c0=0); steps >=1 use Wih+Whh since inp==h.
  for (int t = 0; t < T; ++t) {
    const unsigned short* a = (t % 2 == 0) ? h1 : h2;
    unsigned short* ho      = (t % 2 == 0) ? h2 : h1;
    k_lstm_step<<<dim3(512 / 32, B / 128), 256, 0, stream>>>(
        a, (t == 0) ? Wihb : Wsumb, biasg, cbuf, ho, out, T, t, (t == 0) ? 1 : 0);
  }
}

// Round 4
// 822.380 us; speedup vs baseline: 1.1655x; 1.1347x over previous
//
#include <hip/hip_runtime.h>
#include <hip/hip_bf16.h>

typedef __attribute__((ext_vector_type(8))) short s8v;   // 8 bf16 in 4 VGPRs
typedef __attribute__((ext_vector_type(4))) float f4v;   // 4 fp32 acc

__device__ __forceinline__ void gl_lds16(const void* g, void* l) {
  __builtin_amdgcn_global_load_lds(
      (const __attribute__((address_space(1))) unsigned int*)g,
      (__attribute__((address_space(3))) unsigned int*)l, 16, 0, 0);
}

__device__ __forceinline__ unsigned short f2b(float v) {
  __hip_bfloat16 b = __float2bfloat16(v);  // RNE
  return __builtin_bit_cast(unsigned short, b);
}

// sigm(x) = 1/(1+2^(-x*log2e)) : 2 transcendental + 2 VALU (no div sequence)
__device__ __forceinline__ float sigm(float x) {
  float e = __builtin_amdgcn_exp2f(-1.442695041f * x);
  return __builtin_amdgcn_rcpf(1.0f + e);
}
// tanh(x) = 2*sigm(2x) - 1, saturates cleanly at +-1
__device__ __forceinline__ float tanh_f(float x) {
  float e = __builtin_amdgcn_exp2f(-2.885390082f * x);
  return __builtin_fmaf(2.0f, __builtin_amdgcn_rcpf(1.0f + e), -1.0f);
}

// ---------------- prep kernels ----------------

__global__ void k_conv_bf16(const float* __restrict__ src, unsigned short* __restrict__ dst, int n) {
  int i = blockIdx.x * blockDim.x + threadIdx.x;
  if (i < n) dst[i] = f2b(src[i]);
}

// W1x[n][k] = bf16(W1[n][17+k]) for k in [0,256); b1e[n] = b1[n] + W1[n][20 - slen]
__global__ void k_prep_w1(const float* __restrict__ W1, const float* __restrict__ b1,
                          const int* __restrict__ slen,
                          unsigned short* __restrict__ W1x, float* __restrict__ b1e) {
  int i = blockIdx.x * blockDim.x + threadIdx.x;
  if (i < 512 * 256) {
    int n = i >> 8, k = i & 255;
    W1x[i] = f2b(W1[n * 273 + 17 + k]);
  }
  if (i < 512) {
    int col = 20 - *slen;
    b1e[i] = b1[i] + W1[i * 273 + col];
  }
}

// Wihb = bf16(Wih); Wsum = bf16(Wih+Whh); biasg = bih+bhh
__global__ void k_prep_gates(const float* __restrict__ Wih, const float* __restrict__ Whh,
                             const float* __restrict__ bih, const float* __restrict__ bhh,
                             unsigned short* __restrict__ Wihb, unsigned short* __restrict__ Wsum,
                             float* __restrict__ biasg) {
  int i = blockIdx.x * blockDim.x + threadIdx.x;
  if (i < 2048 * 512) {
    float a = Wih[i];
    Wihb[i] = f2b(a);
    Wsum[i] = f2b(a + Whh[i]);
  }
  if (i < 2048) biasg[i] = bih[i] + bhh[i];
}

// ---------------- GEMM C = act(A @ Bt^T + bias), A:[M,K] bf16, Bt:[N,K] bf16 ----------------
// 128x128 tile, BK=32, 256 threads (4 waves in 2x2), 16x16x32 bf16 MFMA.
// ACT: 0 = relu, 1 = sigmoid. Output bf16.

template <int ACT>
__global__ __launch_bounds__(256)
void k_gemm_bt(const unsigned short* __restrict__ A, const unsigned short* __restrict__ Bt,
               const float* __restrict__ bias, unsigned short* __restrict__ C,
               int M, int N, int K) {
  __shared__ __align__(16) unsigned short As[128 * 32];
  __shared__ __align__(16) unsigned short Bs[128 * 32];
  const int tid = threadIdx.x;
  const int m0 = blockIdx.y * 128, n0 = blockIdx.x * 128;
  const int lane = tid & 63, wave = tid >> 6;
  const int wm = (wave >> 1) * 64, wn = (wave & 1) * 64;
  const int lr = lane & 15, lq = lane >> 4;

  f4v acc[4][4];
#pragma unroll
  for (int i = 0; i < 4; ++i)
#pragma unroll
    for (int j = 0; j < 4; ++j) acc[i][j] = (f4v){0.f, 0.f, 0.f, 0.f};

  for (int k0 = 0; k0 < K; k0 += 32) {
    __syncthreads();  // previous iter's LDS consumers done
#pragma unroll
    for (int s = 0; s < 2; ++s) {
      int cc = tid + s * 256;          // chunk index; lane-contiguous within wave
      int row = cc >> 2, kk = (cc & 3) << 3;
      gl_lds16(&A[(long)(m0 + row) * K + k0 + kk], &As[cc * 8]);
      gl_lds16(&Bt[(long)(n0 + row) * K + k0 + kk], &Bs[cc * 8]);
    }
    __syncthreads();  // drains vmcnt -> LDS valid

    s8v a[4], b[4];
#pragma unroll
    for (int i = 0; i < 4; ++i)
      a[i] = *(const s8v*)&As[(wm + i * 16 + lr) * 32 + lq * 8];
#pragma unroll
    for (int j = 0; j < 4; ++j)
      b[j] = *(const s8v*)&Bs[(wn + j * 16 + lr) * 32 + lq * 8];
#pragma unroll
    for (int i = 0; i < 4; ++i)
#pragma unroll
      for (int j = 0; j < 4; ++j)
        acc[i][j] = __builtin_amdgcn_mfma_f32_16x16x32_bf16(a[i], b[j], acc[i][j], 0, 0, 0);
  }

#pragma unroll
  for (int i = 0; i < 4; ++i) {
#pragma unroll
    for (int j = 0; j < 4; ++j) {
#pragma unroll
      for (int r = 0; r < 4; ++r) {
        int m = m0 + wm + i * 16 + lq * 4 + r;
        int n = n0 + wn + j * 16 + lr;
        float v = acc[i][j][r] + bias[n];
        v = (ACT == 0) ? fmaxf(v, 0.0f) : sigm(v);
        C[(long)m * N + n] = f2b(v);
      }
    }
  }
}

// ---------------- fused LSTM step ----------------
// gates[:, g*512+u] = A @ Wg^T + bias; cell epilogue entirely in-register.
// Block: 256 rows x 32 units x 4 gates. Grid (512/32, M/256) = 512 blocks = 2/CU.
// 4 waves split rows (64 each): 32 MFMA per wave-iter vs 12 ds_read_b128.

__global__ __launch_bounds__(256, 2)
void k_lstm_step(const unsigned short* __restrict__ A,   // [M,512] bf16 (h_prev or x0)
                 const unsigned short* __restrict__ Wg,  // [2048,512] bf16
                 const float* __restrict__ bias,         // [2048] = bih+bhh
                 float* __restrict__ Cst,                // [M,512] fp32 cell state
                 unsigned short* __restrict__ Hout,      // [M,512] bf16 next input
                 float* __restrict__ Out,                // [M,T,512] fp32
                 int T, int t, int first) {
  __shared__ __align__(16) unsigned short As[256 * 32];  // 16 KB
  __shared__ __align__(16) unsigned short Bs[4 * 32 * 32];  // 8 KB
  const int tid = threadIdx.x;
  const int m0 = blockIdx.y * 256;
  const int n0 = blockIdx.x * 32;
  const int lane = tid & 63, wave = tid >> 6;
  const int lr = lane & 15, lq = lane >> 4;
  const int wrow = wave * 64;
  const int K = 512;

  f4v acc[4][4][2];  // [gate][row-tile][col-tile] = 128 VGPRs
#pragma unroll
  for (int g = 0; g < 4; ++g)
#pragma unroll
    for (int i = 0; i < 4; ++i)
#pragma unroll
      for (int j = 0; j < 2; ++j) acc[g][i][j] = (f4v){0.f, 0.f, 0.f, 0.f};

  for (int k0 = 0; k0 < K; k0 += 32) {
    __syncthreads();
    // A tile: 256 rows x 32 -> 1024 chunks of 16B ; B tiles: 4x32x32 -> 512 chunks
#pragma unroll
    for (int s = 0; s < 4; ++s) {
      int cc = tid + s * 256;
      int row = cc >> 2, kk = (cc & 3) << 3;
      gl_lds16(&A[(long)(m0 + row) * K + k0 + kk], &As[cc * 8]);
    }
#pragma unroll
    for (int s = 0; s < 2; ++s) {
      int cc = tid + s * 256;
      int g = cc >> 7, idx = cc & 127;
      int row = idx >> 2, kk = (idx & 3) << 3;
      gl_lds16(&Wg[(long)(g * 512 + n0 + row) * K + k0 + kk], &Bs[cc * 8]);
    }
    __syncthreads();

    s8v a[4], b[4][2];
#pragma unroll
    for (int i = 0; i < 4; ++i)
      a[i] = *(const s8v*)&As[(wrow + i * 16 + lr) * 32 + lq * 8];
#pragma unroll
    for (int g = 0; g < 4; ++g)
#pragma unroll
      for (int j = 0; j < 2; ++j)
        b[g][j] = *(const s8v*)&Bs[g * 1024 + (j * 16 + lr) * 32 + lq * 8];
#pragma unroll
    for (int g = 0; g < 4; ++g)
#pragma unroll
      for (int i = 0; i < 4; ++i)
#pragma unroll
        for (int j = 0; j < 2; ++j)
          acc[g][i][j] = __builtin_amdgcn_mfma_f32_16x16x32_bf16(a[i], b[g][j], acc[g][i][j], 0, 0, 0);
  }

#pragma unroll
  for (int i = 0; i < 4; ++i) {
#pragma unroll
    for (int j = 0; j < 2; ++j) {
#pragma unroll
      for (int r = 0; r < 4; ++r) {
        int m = m0 + wrow + i * 16 + lq * 4 + r;
        int u = n0 + j * 16 + lr;
        float gi = acc[0][i][j][r] + bias[u];
        float gf = acc[1][i][j][r] + bias[512 + u];
        float gg = acc[2][i][j][r] + bias[1024 + u];
        float go = acc[3][i][j][r] + bias[1536 + u];
        float c_old = first ? 0.0f : Cst[(long)m * 512 + u];
        float cn = sigm(gf) * c_old + sigm(gi) * tanh_f(gg);
        float h = sigm(go) * tanh_f(cn);
        Cst[(long)m * 512 + u] = cn;
        Hout[(long)m * 512 + u] = f2b(h);
        __builtin_nontemporal_store(h, &Out[((long)m * T + t) * 512 + u]);
      }
    }
  }
}

// ---------------- launch ----------------

extern "C" void kernel_launch(void* const* d_in, const int* in_sizes, int n_in,
                              void* d_out, int out_size, void* d_ws, size_t ws_size,
                              hipStream_t stream) {
  const float* x   = (const float*)d_in[0];
  const float* W1  = (const float*)d_in[1];
  const float* b1  = (const float*)d_in[2];
  const float* W2  = (const float*)d_in[3];
  const float* b2  = (const float*)d_in[4];
  const float* W3  = (const float*)d_in[5];
  const float* b3  = (const float*)d_in[6];
  const float* Wih = (const float*)d_in[7];
  const float* Whh = (const float*)d_in[8];
  const float* bih = (const float*)d_in[9];
  const float* bhh = (const float*)d_in[10];
  const int* slen  = (const int*)d_in[11];
  float* out = (float*)d_out;

  const int B = in_sizes[0] / 256;     // 8192
  const int T = out_size / (B * 512);  // = sentence_len = 16

  // workspace carve (256B aligned)
  size_t o = 0;
  auto alloc = [&](size_t bytes) {
    o = (o + 255) & ~(size_t)255;
    void* r = (char*)d_ws + o;
    o += bytes;
    return r;
  };
  unsigned short* xb    = (unsigned short*)alloc((size_t)B * 256 * 2);
  unsigned short* W1x   = (unsigned short*)alloc(512 * 256 * 2);
  unsigned short* W2b   = (unsigned short*)alloc(512 * 512 * 2);
  unsigned short* W3b   = (unsigned short*)alloc(512 * 512 * 2);
  unsigned short* Wihb  = (unsigned short*)alloc(2048 * 512 * 2);
  unsigned short* Wsumb = (unsigned short*)alloc(2048 * 512 * 2);
  float* b1e   = (float*)alloc(512 * 4);
  float* biasg = (float*)alloc(2048 * 4);
  unsigned short* h1 = (unsigned short*)alloc((size_t)B * 512 * 2);
  unsigned short* h2 = (unsigned short*)alloc((size_t)B * 512 * 2);
  float* cbuf = (float*)alloc((size_t)B * 512 * 4);
  (void)ws_size;

  // prep
  k_conv_bf16<<<(B * 256 + 255) / 256, 256, 0, stream>>>(x, xb, B * 256);
  k_conv_bf16<<<(512 * 512 + 255) / 256, 256, 0, stream>>>(W2, W2b, 512 * 512);
  k_conv_bf16<<<(512 * 512 + 255) / 256, 256, 0, stream>>>(W3, W3b, 512 * 512);
  k_prep_w1<<<(512 * 256 + 255) / 256, 256, 0, stream>>>(W1, b1, slen, W1x, b1e);
  k_prep_gates<<<(2048 * 512 + 255) / 256, 256, 0, stream>>>(Wih, Whh, bih, bhh, Wihb, Wsumb, biasg);

  // MLP: h1 = relu(x@W1x^T + b1e); h2 = relu(h1@W2^T + b2); x0 = sigmoid(h2@W3^T + b3) -> h1
  k_gemm_bt<0><<<dim3(4, B / 128), 256, 0, stream>>>(xb, W1x, b1e, h1, B, 512, 256);
  k_gemm_bt<0><<<dim3(4, B / 128), 256, 0, stream>>>(h1, W2b, b2, h2, B, 512, 512);
  k_gemm_bt<1><<<dim3(4, B / 128), 256, 0, stream>>>(h2, W3b, b3, h1, B, 512, 512);

  // LSTM: step 0 uses Wih only (h0=0, c0=0); steps >=1 use Wih+Whh since inp==h.
  for (int t = 0; t < T; ++t) {
    const unsigned short* a = (t % 2 == 0) ? h1 : h2;
    unsigned short* ho      = (t % 2 == 0) ? h2 : h1;
    k_lstm_step<<<dim3(512 / 32, B / 256), 256, 0, stream>>>(
        a, (t == 0) ? Wihb : Wsumb, biasg, cbuf, ho, out, T, t, (t == 0) ? 1 : 0);
  }
}